// Round 12
// baseline (515.500 us; speedup 1.0000x reference)
//
#include <hip/hip_runtime.h>
#include <math.h>

#define NN 50000
#define NE 800000

__device__ __forceinline__ float elu1(float x) { return x > 0.f ? x : expm1f(x); }
__device__ __forceinline__ float lrelu(float x) { return x >= 0.f ? x : 0.2f * x; }

// ---------------- zero cnt (must precede fatA's edge_rank half)
__global__ __launch_bounds__(256) void zero_cnt(int* __restrict__ cnt) {
  int i = blockIdx.x * blockDim.x + threadIdx.x;
  if (i < NN) cnt[i] = 0;
}

// ---------------- fatA: combine_weights (65) || zero degw (391) || edge_rank (3125)
#define FATA_CB 65
#define FATA_ZB 391  // (2*NN+255)/256
__global__ __launch_bounds__(256) void fatA_kernel(
    const float* __restrict__ Wn, const float* __restrict__ bn,
    const float* __restrict__ W1s, const float* __restrict__ b1s,
    const float* __restrict__ W1d, const float* __restrict__ b1d,
    float* __restrict__ Wns, float* __restrict__ Wnd,
    float* __restrict__ bns, float* __restrict__ bnd,
    float* __restrict__ degw_z,
    const int* __restrict__ dst, int* __restrict__ cnt, int* __restrict__ rank) {
  if (blockIdx.x < FATA_CB) {
    int t = blockIdx.x * 256 + threadIdx.x;
    if (t < 8192) {
      int i = t >> 6, o = t & 63;
      float acc = 0.f;
      for (int k = 0; k < 128; ++k) acc += Wn[i * 128 + k] * W1s[k * 64 + o];
      Wns[t] = acc;
    } else if (t < 16384) {
      int u = t - 8192;
      int i = u >> 6, o = u & 63;
      float acc = 0.f;
      for (int k = 0; k < 128; ++k) acc += Wn[i * 128 + k] * W1d[k * 64 + o];
      Wnd[u] = acc;
    } else if (t < 16448) {
      int o = t - 16384;
      float acc = b1s[o];
      for (int k = 0; k < 128; ++k) acc += bn[k] * W1s[k * 64 + o];
      bns[o] = acc;
    } else if (t < 16512) {
      int o = t - 16448;
      float acc = b1d[o];
      for (int k = 0; k < 128; ++k) acc += bn[k] * W1d[k * 64 + o];
      bnd[o] = acc;
    }
  } else if (blockIdx.x < FATA_CB + FATA_ZB) {
    int i = (blockIdx.x - FATA_CB) * 256 + threadIdx.x;  // zero degw (2N words)
    if (i < 2 * NN) degw_z[i] = 0.f;
  } else {
    int e = (blockIdx.x - FATA_CB - FATA_ZB) * 256 + threadIdx.x;
    if (e < NE) rank[e] = atomicAdd(&cnt[dst[e]], 1);
  }
}

// ---------------- single-block exclusive scan of cnt -> row_start (row_start[NN]=NE)
__global__ __launch_bounds__(1024) void scan_all(const int* __restrict__ cnt,
                                                 int* __restrict__ row_start) {
  __shared__ int sh[1024];
  int t = threadIdx.x;
  const int CHUNK = (NN + 1023) / 1024;  // 49
  int base = t * CHUNK;
  int lim = base + CHUNK;
  if (lim > NN) lim = NN;
  int s = 0;
#pragma unroll 8
  for (int i = base; i < lim; ++i) s += cnt[i];
  sh[t] = s;
  __syncthreads();
  for (int off = 1; off < 1024; off <<= 1) {
    int add = (t >= off) ? sh[t - off] : 0;
    __syncthreads();
    sh[t] += add;
    __syncthreads();
  }
  int run = sh[t] - s;  // exclusive prefix
#pragma unroll 8
  for (int i = base; i < lim; ++i) {
    row_start[i] = run;
    run += cnt[i];
  }
  if (base < NN && base + CHUNK >= NN) row_start[NN] = run;
}

// ---------------- reusable GEMM body: Y[N,M] = f(X)[N,K] @ W (+b), 4 rows/thread
template <int K, int M, bool ELU_IN, bool DUAL>
__device__ __forceinline__ void gemm_body(int blk, float* __restrict__ xs,
                                          const float* __restrict__ X,
                                          const float* __restrict__ W1,
                                          const float* __restrict__ b1,
                                          const float* __restrict__ W2,
                                          const float* __restrict__ b2,
                                          float* __restrict__ Y1,
                                          float* __restrict__ Y2) {
  constexpr int RPT = 4;
  constexpr int ROWS = (256 / M) * RPT;
  int row0 = blk * ROWS;
  int t = threadIdx.x;
  for (int idx = t; idx < ROWS * K; idx += 256) {
    int r = idx / K, k = idx - r * K;
    int row = row0 + r;
    float v = (row < NN) ? X[row * K + k] : 0.f;
    if (ELU_IN) v = elu1(v);
    xs[r * K + k] = v;
  }
  __syncthreads();
  int m = t % M, rg = t / M;
  int rbase = rg * RPT;
  float acc1[RPT], acc2[RPT];
#pragma unroll
  for (int j = 0; j < RPT; ++j) {
    acc1[j] = b1 ? b1[m] : 0.f;
    if (DUAL) acc2[j] = b2 ? b2[m] : 0.f;
  }
#pragma unroll 4
  for (int k = 0; k < K; ++k) {
    float w1 = W1[k * M + m];
    float w2 = DUAL ? W2[k * M + m] : 0.f;
#pragma unroll
    for (int j = 0; j < RPT; ++j) {
      float x = xs[(rbase + j) * K + k];
      acc1[j] += x * w1;
      if (DUAL) acc2[j] += x * w2;
    }
  }
#pragma unroll
  for (int j = 0; j < RPT; ++j) {
    int row = row0 + rbase + j;
    if (row >= NN) continue;
    Y1[row * M + m] = acc1[j];
    if (DUAL) Y2[row * M + m] = acc2[j];
  }
}

// ---------------- fatB: even blocks place edges (no position atomic) + degw atomic;
//                  odd blocks run layer-1 dual GEMM (independent).
__global__ __launch_bounds__(256) void fatB_kernel(
    const int* __restrict__ src, const int* __restrict__ dst,
    const float* __restrict__ ew, const int* __restrict__ row_start,
    const int* __restrict__ rank, int2* __restrict__ psrcw,
    unsigned long long* __restrict__ degw,
    const float* __restrict__ h, const float* __restrict__ Wns,
    const float* __restrict__ bns, const float* __restrict__ Wnd,
    const float* __restrict__ bnd, float* __restrict__ FS, float* __restrict__ FD) {
  __shared__ float xs[16 * 128];
  int c = blockIdx.x >> 1;
  if (blockIdx.x & 1) {
    gemm_body<128, 64, false, true>(c, xs, h, Wns, bns, Wnd, bnd, FS, FD);
  } else {
    int e = c * 256 + threadIdx.x;
    if (e >= NE) return;
    int s = src[e], d = dst[e];
    float w = ew[e];
    psrcw[row_start[d] + rank[e]] = make_int2(s, __float_as_int(w));
    unsigned long long pk = (1ULL << 44) | (unsigned long long)(w * 4294967296.0f);
    atomicAdd(&degw[s], pk);
  }
}

// ---------------- fatL2: layer-2 dual GEMM || decode degrees
__global__ __launch_bounds__(256) void fatL2_kernel(
    const float* __restrict__ G, const float* __restrict__ W2s,
    const float* __restrict__ b2s, const float* __restrict__ W2d,
    const float* __restrict__ b2d, float* __restrict__ FS, float* __restrict__ FD,
    const unsigned long long* __restrict__ degw, float* __restrict__ deg) {
  __shared__ float xs[16 * 64];
  if (blockIdx.x < 3125) {
    gemm_body<64, 64, true, true>(blockIdx.x, xs, G, W2s, b2s, W2d, b2d, FS, FD);
  } else {
    int i = (blockIdx.x - 3125) * 256 + threadIdx.x;
    if (i >= NN) return;
    unsigned long long v = degw[i];
    deg[i] = (float)((double)(v & ((1ULL << 44) - 1)) * (1.0 / 4294967296.0));
    deg[NN + i] = (float)(v >> 44);
  }
}

// ---------------- Fused GATv2 layer (wave per dst node, 8-way unrolled).
// HALFW: 1 -> 2 heads x 32 (reduce over 32-lane halves); 0 -> 1 head x 64.
// FUSE_YM: epilogue computes ym = elu(g) @ Wc1 * rsqrt(outw) (32 wide) instead of storing g.
template <int HALFW, int FUSE_YM>
__global__ __launch_bounds__(256) void gat_fused(const int* __restrict__ row_start,
                                                 const int2* __restrict__ psrcw,
                                                 const float* __restrict__ fs,
                                                 const float* __restrict__ fd,
                                                 const float* __restrict__ attn,
                                                 const float* __restrict__ Wc1,
                                                 const float* __restrict__ wdeg_out,
                                                 float* __restrict__ g) {
  __shared__ float wlds[FUSE_YM ? 64 * 32 : 1];
  if (FUSE_YM) {
    for (int idx = threadIdx.x; idx < 2048; idx += 256) wlds[idx] = Wc1[idx];
    __syncthreads();
  }
  int n = blockIdx.x * 4 + (threadIdx.x >> 6);  // NN % 4 == 0 -> n < NN always
  int lane = threadIdx.x & 63;
  int beg = row_start[n], end = row_start[n + 1];
  float fdv = fd[n * 64 + lane];
  float av = attn[lane];
  float acc = 0.f, den = 0.f;
  int i = beg;
  for (; i + 7 < end; i += 8) {
    float f[8], v[8];
#pragma unroll
    for (int j = 0; j < 8; ++j) f[j] = fs[psrcw[i + j].x * 64 + lane];
#pragma unroll
    for (int j = 0; j < 8; ++j) v[j] = lrelu(f[j] + fdv) * av;
#pragma unroll
    for (int m = 16; m >= 1; m >>= 1) {
#pragma unroll
      for (int j = 0; j < 8; ++j) v[j] += __shfl_xor(v[j], m, 64);
    }
    if (!HALFW) {
#pragma unroll
      for (int j = 0; j < 8; ++j) v[j] += __shfl_xor(v[j], 32, 64);
    }
#pragma unroll
    for (int j = 0; j < 8; ++j) {
      float p = __expf(v[j]);  // softmax shift-invariant; logits tiny -> no max pass
      acc += f[j] * p;
      den += p;
    }
  }
  for (; i < end; ++i) {
    int s = psrcw[i].x;
    float fsv = fs[s * 64 + lane];
    float v = lrelu(fsv + fdv) * av;
#pragma unroll
    for (int m = 16; m >= 1; m >>= 1) v += __shfl_xor(v, m, 64);
    if (!HALFW) v += __shfl_xor(v, 32, 64);
    float p = __expf(v);
    acc += fsv * p;
    den += p;
  }
  float gv = (end > beg) ? acc / den : 0.f;
  if (!FUSE_YM) {
    g[n * 64 + lane] = gv;
  } else {
    // ym[n][m] = rsqrt_guard(outw[n]) * sum_k elu(g[n][k]) * Wc1[k][m], m < 32
    float xv = elu1(gv);
    float accm = 0.f;
#pragma unroll 8
    for (int k = 0; k < 64; ++k) accm += __shfl(xv, k, 64) * wlds[k * 32 + (lane & 31)];
    if (lane < 32) {
      float wv = wdeg_out[n];
      float rs = (wv > 0.f) ? rsqrtf(wv) : 0.f;
      g[n * 32 + lane] = accm * rs;
    }
  }
}

// ---------------- Fused GraphConv1 + xs GEMM epilogue:
//   c1[n][f] = rsqrt(inw) * sum_e w_e * ym[src_e][f];  x3 = elu(c1 + bc1)
//   xs[n][m] = rsqrt(max(dout,1)) * sum_f x3[f] * Wc2[f][m], m < 16
__global__ __launch_bounds__(256) void gconv1x_kernel(const int* __restrict__ row_start,
                                                      const int2* __restrict__ psrcw,
                                                      const float* __restrict__ ym,
                                                      const float* __restrict__ bc1,
                                                      const float* __restrict__ Wc2,
                                                      const float* __restrict__ cnt_out,
                                                      float* __restrict__ xsout) {
  __shared__ float w2[32 * 16];
  for (int idx = threadIdx.x; idx < 512; idx += 256) w2[idx] = Wc2[idx];
  __syncthreads();
  int n = blockIdx.x * 4 + (threadIdx.x >> 6);
  int lane = threadIdx.x & 63;
  int half = lane >> 5, f = lane & 31;
  int beg = row_start[n], end = row_start[n + 1];
  float acc = 0.f, wsum = 0.f;
  int i = beg + half;
  for (; i + 2 < end; i += 4) {
    int2 a = psrcw[i], b = psrcw[i + 2];
    float wa = __int_as_float(a.y), wb = __int_as_float(b.y);
    acc += ym[a.x * 32 + f] * wa + ym[b.x * 32 + f] * wb;
    wsum += wa + wb;
  }
  if (i < end) {
    int2 a = psrcw[i];
    float wa = __int_as_float(a.y);
    acc += ym[a.x * 32 + f] * wa;
    wsum += wa;
  }
  acc += __shfl_xor(acc, 32, 64);
  wsum += __shfl_xor(wsum, 32, 64);
  // all 64 lanes now hold the full-row sums (mirrored halves)
  float x3v = elu1(((end > beg) ? acc * rsqrtf(wsum) : 0.f) + bc1[f]);
  float accm = 0.f;
#pragma unroll 8
  for (int k = 0; k < 32; ++k) accm += __shfl(x3v, k, 64) * w2[k * 16 + (lane & 15)];
  if (lane < 16) xsout[n * 16 + lane] = accm * rsqrtf(fmaxf(cnt_out[n], 1.f));
}

// ---------------- Fused GraphConv2
__global__ __launch_bounds__(256) void gconv2_fused(const int* __restrict__ row_start,
                                                    const int2* __restrict__ psrcw,
                                                    const float* __restrict__ xs,
                                                    const float* __restrict__ bc2,
                                                    float* __restrict__ x4) {
  int n = blockIdx.x * 4 + (threadIdx.x >> 6);
  if (n >= NN) return;
  int lane = threadIdx.x & 63;
  int q = lane >> 4, f = lane & 15;
  int beg = row_start[n], end = row_start[n + 1];
  float acc = 0.f;
  int i = beg + q;
  for (; i + 4 < end; i += 8) acc += xs[psrcw[i].x * 16 + f] + xs[psrcw[i + 4].x * 16 + f];
  if (i < end) acc += xs[psrcw[i].x * 16 + f];
  acc += __shfl_xor(acc, 16, 64);
  acc += __shfl_xor(acc, 32, 64);
  if (lane < 16) {
    float len = (float)(end - beg);
    x4[n * 16 + lane] = elu1(acc * rsqrtf(fmaxf(len, 1.f)) + bc2[lane]);
  }
}

// ---------------- classifier: 2 threads/edge, float4 loads + float4 store
__global__ __launch_bounds__(256) void classifier_kernel(const int* __restrict__ src,
                                                         const int* __restrict__ dst,
                                                         const float* __restrict__ x4,
                                                         const float* __restrict__ Wcls,
                                                         const float* __restrict__ bcls,
                                                         float* __restrict__ out) {
  __shared__ float w[256];
  __shared__ float bb[8];
  if (threadIdx.x < 256) w[threadIdx.x] = Wcls[threadIdx.x];
  if (threadIdx.x < 8) bb[threadIdx.x] = bcls[threadIdx.x];
  __syncthreads();
  int t = blockIdx.x * blockDim.x + threadIdx.x;
  int e = t >> 1, c0 = (t & 1) * 4;
  if (e >= NE) return;
  int s = src[e], d = dst[e];
  const float4* xsv = (const float4*)&x4[s * 16];
  const float4* xdv = (const float4*)&x4[d * 16];
  float acc0 = bb[c0], acc1 = bb[c0 + 1], acc2 = bb[c0 + 2], acc3 = bb[c0 + 3];
#pragma unroll
  for (int q = 0; q < 4; ++q) {
    float4 xv = xsv[q];
#pragma unroll
    for (int j = 0; j < 4; ++j) {
      float x = j == 0 ? xv.x : j == 1 ? xv.y : j == 2 ? xv.z : xv.w;
      const float* wr = &w[(q * 4 + j) * 8 + c0];
      acc0 += x * wr[0];
      acc1 += x * wr[1];
      acc2 += x * wr[2];
      acc3 += x * wr[3];
    }
  }
#pragma unroll
  for (int q = 0; q < 4; ++q) {
    float4 xv = xdv[q];
#pragma unroll
    for (int j = 0; j < 4; ++j) {
      float x = j == 0 ? xv.x : j == 1 ? xv.y : j == 2 ? xv.z : xv.w;
      const float* wr = &w[(16 + q * 4 + j) * 8 + c0];
      acc0 += x * wr[0];
      acc1 += x * wr[1];
      acc2 += x * wr[2];
      acc3 += x * wr[3];
    }
  }
  *(float4*)&out[e * 8 + c0] = make_float4(acc0, acc1, acc2, acc3);
}

extern "C" void kernel_launch(void* const* d_in, const int* in_sizes, int n_in,
                              void* d_out, int out_size, void* d_ws, size_t ws_size,
                              hipStream_t stream) {
  const float* h      = (const float*)d_in[0];
  const float* edge_w = (const float*)d_in[1];
  const int*   src    = (const int*)d_in[2];
  const int*   dst    = (const int*)d_in[3];
  const float* Wn    = (const float*)d_in[4];
  const float* bn    = (const float*)d_in[5];
  const float* W1s   = (const float*)d_in[6];
  const float* b1s   = (const float*)d_in[7];
  const float* W1d   = (const float*)d_in[8];
  const float* b1d   = (const float*)d_in[9];
  const float* attn1 = (const float*)d_in[10];
  const float* W2s   = (const float*)d_in[11];
  const float* b2s   = (const float*)d_in[12];
  const float* W2d   = (const float*)d_in[13];
  const float* b2d   = (const float*)d_in[14];
  const float* attn2 = (const float*)d_in[15];
  const float* Wc1   = (const float*)d_in[16];
  const float* bc1   = (const float*)d_in[17];
  const float* Wc2   = (const float*)d_in[18];
  const float* bc2   = (const float*)d_in[19];
  const float* Wcls  = (const float*)d_in[20];
  const float* bcls  = (const float*)d_in[21];
  float* out = (float*)d_out;

  float* ws = (float*)d_ws;
  size_t off = 0;
  // round every allocation to 4 floats so int2/float4 views stay 16B-aligned
  auto alloc = [&](size_t nf) { float* pp = ws + off; off += (nf + 3) & ~(size_t)3; return pp; };
  float* Wns = alloc(8192);
  float* Wnd = alloc(8192);
  float* bns = alloc(64);
  float* bnd = alloc(64);
  unsigned long long* degw = (unsigned long long*)alloc(2 * NN);  // u64 per node
  int*   cnt = (int*)alloc(NN);
  float* deg = alloc(2 * NN);          // decoded wdeg_out | cnt_out (fully written)
  int*   row_start = (int*)alloc(NN + 1);
  int2*  psrcw = (int2*)alloc(2 * NE); // dst-sorted (src, weight_bits)
  float* FS  = alloc(64 * NN);         // fs1 -> fs2 -> x4(16N)
  float* FD  = alloc(64 * NN);         // fd1 -> fd2 -> xs(16N)
  float* G   = alloc(64 * NN);         // rank -> g1 -> ym(32N)
  int*   rank = (int*)G;               // rank dead before gat1 writes G

  dim3 b256(256);
  const int EB = (NE + 255) / 256;     // 3125
  const int NB4 = (NN + 3) / 4;        // 12500

  // 1. zero cnt (edge_rank dependency)
  zero_cnt<<<(NN + 255) / 256, b256, 0, stream>>>(cnt);
  // 2. combine weights || zero degw || per-edge dst rank
  fatA_kernel<<<FATA_CB + FATA_ZB + EB, b256, 0, stream>>>(
      Wn, bn, W1s, b1s, W1d, b1d, Wns, Wnd, bns, bnd, (float*)degw, dst, cnt, rank);
  // 3. row_start = exclusive scan of cnt (single block)
  scan_all<<<1, 1024, 0, stream>>>(cnt, row_start);
  // 4. place edges (no position atomic) + degw atomics  ||  layer-1 dual GEMM
  fatB_kernel<<<2 * EB, b256, 0, stream>>>(src, dst, edge_w, row_start, rank, psrcw,
                                           degw, h, Wns, bns, Wnd, bnd, FS, FD);
  // 5. GAT layer 1
  gat_fused<1, 0><<<NB4, b256, 0, stream>>>(row_start, psrcw, FS, FD, attn1,
                                            nullptr, nullptr, G);
  // 6. layer-2 dual GEMM || decode degrees
  fatL2_kernel<<<3125 + (NN + 255) / 256, b256, 0, stream>>>(G, W2s, b2s, W2d, b2d,
                                                             FS, FD, degw, deg);
  // 7. GAT layer 2 + fused ym epilogue (ym -> G, 32 wide)
  gat_fused<0, 1><<<NB4, b256, 0, stream>>>(row_start, psrcw, FS, FD, attn2,
                                            Wc1, deg, G);
  // 8. GraphConv1 aggregate + fused xs GEMM (xs -> FD, 16 wide)
  gconv1x_kernel<<<NB4, b256, 0, stream>>>(row_start, psrcw, G, bc1, Wc2, deg + NN, FD);
  // 9. GraphConv2 aggregate (x4 -> FS)
  gconv2_fused<<<NB4, b256, 0, stream>>>(row_start, psrcw, FD, bc2, FS);
  // 10. per-edge classifier
  classifier_kernel<<<(NE * 2 + 255) / 256, b256, 0, stream>>>(src, dst, FS, Wcls, bcls, out);
}

// Round 14
// 472.159 us; speedup vs baseline: 1.0918x; 1.0918x over previous
//
#include <hip/hip_runtime.h>
#include <math.h>

#define NN 50000
#define NE 800000

__device__ __forceinline__ float elu1(float x) { return x > 0.f ? x : expm1f(x); }
__device__ __forceinline__ float lrelu(float x) { return x >= 0.f ? x : 0.2f * x; }

// ---------------- zero cnt (must precede fatA's edge_rank section)
__global__ __launch_bounds__(256) void zero_cnt(int* __restrict__ cnt) {
  int i = blockIdx.x * blockDim.x + threadIdx.x;
  if (i < NN) cnt[i] = 0;
}

// ---------------- fatA: combine_weights (65) || zero degw (391) || edge_rank (3125)
#define FATA_CB 65
#define FATA_ZB 391  // (2*NN+255)/256
__global__ __launch_bounds__(256) void fatA_kernel(
    const float* __restrict__ Wn, const float* __restrict__ bn,
    const float* __restrict__ W1s, const float* __restrict__ b1s,
    const float* __restrict__ W1d, const float* __restrict__ b1d,
    float* __restrict__ Wns, float* __restrict__ Wnd,
    float* __restrict__ bns, float* __restrict__ bnd,
    float* __restrict__ degw_z,
    const int* __restrict__ dst, int* __restrict__ cnt, int* __restrict__ rank) {
  if (blockIdx.x < FATA_CB) {
    int t = blockIdx.x * 256 + threadIdx.x;
    if (t < 8192) {
      int i = t >> 6, o = t & 63;
      float acc = 0.f;
      for (int k = 0; k < 128; ++k) acc += Wn[i * 128 + k] * W1s[k * 64 + o];
      Wns[t] = acc;
    } else if (t < 16384) {
      int u = t - 8192;
      int i = u >> 6, o = u & 63;
      float acc = 0.f;
      for (int k = 0; k < 128; ++k) acc += Wn[i * 128 + k] * W1d[k * 64 + o];
      Wnd[u] = acc;
    } else if (t < 16448) {
      int o = t - 16384;
      float acc = b1s[o];
      for (int k = 0; k < 128; ++k) acc += bn[k] * W1s[k * 64 + o];
      bns[o] = acc;
    } else if (t < 16512) {
      int o = t - 16448;
      float acc = b1d[o];
      for (int k = 0; k < 128; ++k) acc += bn[k] * W1d[k * 64 + o];
      bnd[o] = acc;
    }
  } else if (blockIdx.x < FATA_CB + FATA_ZB) {
    int i = (blockIdx.x - FATA_CB) * 256 + threadIdx.x;  // zero degw (2N words)
    if (i < 2 * NN) degw_z[i] = 0.f;
  } else {
    int e = (blockIdx.x - FATA_CB - FATA_ZB) * 256 + threadIdx.x;
    if (e < NE) rank[e] = atomicAdd(&cnt[dst[e]], 1);
  }
}

// ---------------- single-block exclusive scan of cnt -> row_start (row_start[NN]=NE)
__global__ __launch_bounds__(1024) void scan_all(const int* __restrict__ cnt,
                                                 int* __restrict__ row_start) {
  __shared__ int sh[1024];
  int t = threadIdx.x;
  const int CHUNK = (NN + 1023) / 1024;  // 49
  int base = t * CHUNK;
  int lim = base + CHUNK;
  if (lim > NN) lim = NN;
  int s = 0;
#pragma unroll 8
  for (int i = base; i < lim; ++i) s += cnt[i];
  sh[t] = s;
  __syncthreads();
  for (int off = 1; off < 1024; off <<= 1) {
    int add = (t >= off) ? sh[t - off] : 0;
    __syncthreads();
    sh[t] += add;
    __syncthreads();
  }
  int run = sh[t] - s;  // exclusive prefix
#pragma unroll 8
  for (int i = base; i < lim; ++i) {
    row_start[i] = run;
    run += cnt[i];
  }
  if (base < NN && base + CHUNK >= NN) row_start[NN] = run;
}

// ---------------- reusable GEMM body: Y[N,M] = f(X)[N,K] @ W (+b), 4 rows/thread
//   RS=1: *= rsqrt(max(cnt,1)); RS=2: *= cnt>0 ? rsqrt(cnt) : 0
template <int K, int M, bool ELU_IN, int RS, bool DUAL>
__device__ __forceinline__ void gemm_body(int blk, float* __restrict__ xs,
                                          const float* __restrict__ X,
                                          const float* __restrict__ W1,
                                          const float* __restrict__ b1,
                                          const float* __restrict__ W2,
                                          const float* __restrict__ b2,
                                          const float* __restrict__ cnt,
                                          float* __restrict__ Y1,
                                          float* __restrict__ Y2) {
  constexpr int RPT = 4;
  constexpr int ROWS = (256 / M) * RPT;
  int row0 = blk * ROWS;
  int t = threadIdx.x;
  for (int idx = t; idx < ROWS * K; idx += 256) {
    int r = idx / K, k = idx - r * K;
    int row = row0 + r;
    float v = (row < NN) ? X[row * K + k] : 0.f;
    if (ELU_IN) v = elu1(v);
    xs[r * K + k] = v;
  }
  __syncthreads();
  int m = t % M, rg = t / M;
  int rbase = rg * RPT;
  float acc1[RPT], acc2[RPT];
#pragma unroll
  for (int j = 0; j < RPT; ++j) {
    acc1[j] = b1 ? b1[m] : 0.f;
    if (DUAL) acc2[j] = b2 ? b2[m] : 0.f;
  }
#pragma unroll 4
  for (int k = 0; k < K; ++k) {
    float w1 = W1[k * M + m];
    float w2 = DUAL ? W2[k * M + m] : 0.f;
#pragma unroll
    for (int j = 0; j < RPT; ++j) {
      float x = xs[(rbase + j) * K + k];
      acc1[j] += x * w1;
      if (DUAL) acc2[j] += x * w2;
    }
  }
#pragma unroll
  for (int j = 0; j < RPT; ++j) {
    int row = row0 + rbase + j;
    if (row >= NN) continue;
    float sc = 1.f;
    if (RS == 1) sc = rsqrtf(fmaxf(cnt[row], 1.f));
    if (RS == 2) {
      float wv = cnt[row];
      sc = (wv > 0.f) ? rsqrtf(wv) : 0.f;
    }
    Y1[row * M + m] = acc1[j] * sc;
    if (DUAL) Y2[row * M + m] = acc2[j] * sc;
  }
}

template <int K, int M, bool ELU_IN, int RS, bool DUAL>
__global__ __launch_bounds__(256) void node_gemm(const float* __restrict__ X,
                                                 const float* __restrict__ W1,
                                                 const float* __restrict__ b1,
                                                 const float* __restrict__ W2,
                                                 const float* __restrict__ b2,
                                                 const float* __restrict__ cnt,
                                                 float* __restrict__ Y1,
                                                 float* __restrict__ Y2) {
  __shared__ float xs[(256 / M) * 4 * K];
  gemm_body<K, M, ELU_IN, RS, DUAL>(blockIdx.x, xs, X, W1, b1, W2, b2, cnt, Y1, Y2);
}

// ---------------- fatB: even blocks place edges (no position atomic) + degw atomic;
//                  odd blocks run layer-1 dual GEMM (independent).
__global__ __launch_bounds__(256) void fatB_kernel(
    const int* __restrict__ src, const int* __restrict__ dst,
    const float* __restrict__ ew, const int* __restrict__ row_start,
    const int* __restrict__ rank, int2* __restrict__ psrcw,
    unsigned long long* __restrict__ degw,
    const float* __restrict__ h, const float* __restrict__ Wns,
    const float* __restrict__ bns, const float* __restrict__ Wnd,
    const float* __restrict__ bnd, float* __restrict__ FS, float* __restrict__ FD) {
  __shared__ float xs[16 * 128];
  int c = blockIdx.x >> 1;
  if (blockIdx.x & 1) {
    gemm_body<128, 64, false, 0, true>(c, xs, h, Wns, bns, Wnd, bnd, nullptr, FS, FD);
  } else {
    int e = c * 256 + threadIdx.x;
    if (e >= NE) return;
    int s = src[e], d = dst[e];
    float w = ew[e];
    psrcw[row_start[d] + rank[e]] = make_int2(s, __float_as_int(w));
    unsigned long long pk = (1ULL << 44) | (unsigned long long)(w * 4294967296.0f);
    atomicAdd(&degw[s], pk);
  }
}

// ---------------- fatL2: layer-2 dual GEMM || decode degrees
__global__ __launch_bounds__(256) void fatL2_kernel(
    const float* __restrict__ G, const float* __restrict__ W2s,
    const float* __restrict__ b2s, const float* __restrict__ W2d,
    const float* __restrict__ b2d, float* __restrict__ FS, float* __restrict__ FD,
    const unsigned long long* __restrict__ degw, float* __restrict__ deg) {
  __shared__ float xs[16 * 64];
  if (blockIdx.x < 3125) {
    gemm_body<64, 64, true, 0, true>(blockIdx.x, xs, G, W2s, b2s, W2d, b2d, nullptr, FS, FD);
  } else {
    int i = (blockIdx.x - 3125) * 256 + threadIdx.x;
    if (i >= NN) return;
    unsigned long long v = degw[i];
    deg[i] = (float)((double)(v & ((1ULL << 44) - 1)) * (1.0 / 4294967296.0));
    deg[NN + i] = (float)(v >> 44);
  }
}

// ---------------- Fused GATv2 layer: wave per dst node, 4-way with software pipeline
// (next group's gathers issued BEFORE current group's shuffle/exp block).
// HALFW: 1 -> 2 heads x 32 (reduce over 32-lane halves); 0 -> 1 head x 64.
template <int HALFW>
__global__ __launch_bounds__(256) void gat_fused(const int* __restrict__ row_start,
                                                 const int2* __restrict__ psrcw,
                                                 const float* __restrict__ fs,
                                                 const float* __restrict__ fd,
                                                 const float* __restrict__ attn,
                                                 float* __restrict__ g) {
  int n = blockIdx.x * 4 + (threadIdx.x >> 6);
  if (n >= NN) return;
  int lane = threadIdx.x & 63;
  int beg = row_start[n], end = row_start[n + 1];
  float fdv = fd[n * 64 + lane];
  float av = attn[lane];
  float acc = 0.f, den = 0.f;
  int i = beg;
  float fc[4];
  bool have = (i + 3 < end);
  if (have) {
#pragma unroll
    for (int j = 0; j < 4; ++j) fc[j] = fs[psrcw[i + j].x * 64 + lane];
  }
  while (have) {
    int inext = i + 4;
    bool havenext = (inext + 3 < end);
    float fn[4];
    if (havenext) {  // prefetch next group before current group's VALU chain
#pragma unroll
      for (int j = 0; j < 4; ++j) fn[j] = fs[psrcw[inext + j].x * 64 + lane];
    }
    float v[4];
#pragma unroll
    for (int j = 0; j < 4; ++j) v[j] = lrelu(fc[j] + fdv) * av;
#pragma unroll
    for (int m = 16; m >= 1; m >>= 1) {
#pragma unroll
      for (int j = 0; j < 4; ++j) v[j] += __shfl_xor(v[j], m, 64);
    }
    if (!HALFW) {
#pragma unroll
      for (int j = 0; j < 4; ++j) v[j] += __shfl_xor(v[j], 32, 64);
    }
#pragma unroll
    for (int j = 0; j < 4; ++j) {
      float p = __expf(v[j]);  // softmax shift-invariant; logits tiny -> no max pass
      acc += fc[j] * p;
      den += p;
    }
    if (havenext) {
#pragma unroll
      for (int j = 0; j < 4; ++j) fc[j] = fn[j];
    }
    i = inext;
    have = havenext;
  }
  for (; i < end; ++i) {
    int s = psrcw[i].x;
    float fsv = fs[s * 64 + lane];
    float v = lrelu(fsv + fdv) * av;
#pragma unroll
    for (int m = 16; m >= 1; m >>= 1) v += __shfl_xor(v, m, 64);
    if (!HALFW) v += __shfl_xor(v, 32, 64);
    float p = __expf(v);
    acc += fsv * p;
    den += p;
  }
  g[n * 64 + lane] = (end > beg) ? acc / den : 0.f;
}

// ---------------- Fused GraphConv1 (ym carries rsqrt(outw); inw from row weight sum)
__global__ __launch_bounds__(256) void gconv1_fused(const int* __restrict__ row_start,
                                                    const int2* __restrict__ psrcw,
                                                    const float* __restrict__ ym,
                                                    const float* __restrict__ bc1,
                                                    float* __restrict__ x3a) {
  int n = blockIdx.x * 4 + (threadIdx.x >> 6);
  if (n >= NN) return;
  int lane = threadIdx.x & 63;
  int half = lane >> 5, f = lane & 31;
  int beg = row_start[n], end = row_start[n + 1];
  float acc = 0.f, wsum = 0.f;
  int i = beg + half;
  for (; i + 2 < end; i += 4) {
    int2 a = psrcw[i], b = psrcw[i + 2];
    float wa = __int_as_float(a.y), wb = __int_as_float(b.y);
    acc += ym[a.x * 32 + f] * wa + ym[b.x * 32 + f] * wb;
    wsum += wa + wb;
  }
  if (i < end) {
    int2 a = psrcw[i];
    float wa = __int_as_float(a.y);
    acc += ym[a.x * 32 + f] * wa;
    wsum += wa;
  }
  acc += __shfl_xor(acc, 32, 64);
  wsum += __shfl_xor(wsum, 32, 64);
  if (lane < 32) {
    float r = (end > beg) ? acc * rsqrtf(wsum) : 0.f;
    x3a[n * 32 + lane] = elu1(r + bc1[lane]);
  }
}

// ---------------- Fused GraphConv2
__global__ __launch_bounds__(256) void gconv2_fused(const int* __restrict__ row_start,
                                                    const int2* __restrict__ psrcw,
                                                    const float* __restrict__ xs,
                                                    const float* __restrict__ bc2,
                                                    float* __restrict__ x4) {
  int n = blockIdx.x * 4 + (threadIdx.x >> 6);
  if (n >= NN) return;
  int lane = threadIdx.x & 63;
  int q = lane >> 4, f = lane & 15;
  int beg = row_start[n], end = row_start[n + 1];
  float acc = 0.f;
  int i = beg + q;
  for (; i + 4 < end; i += 8) acc += xs[psrcw[i].x * 16 + f] + xs[psrcw[i + 4].x * 16 + f];
  if (i < end) acc += xs[psrcw[i].x * 16 + f];
  acc += __shfl_xor(acc, 16, 64);
  acc += __shfl_xor(acc, 32, 64);
  if (lane < 16) {
    float len = (float)(end - beg);
    x4[n * 16 + lane] = elu1(acc * rsqrtf(fmaxf(len, 1.f)) + bc2[lane]);
  }
}

// ---------------- classifier: 2 threads/edge, float4 loads + float4 store
__global__ __launch_bounds__(256) void classifier_kernel(const int* __restrict__ src,
                                                         const int* __restrict__ dst,
                                                         const float* __restrict__ x4,
                                                         const float* __restrict__ Wcls,
                                                         const float* __restrict__ bcls,
                                                         float* __restrict__ out) {
  __shared__ float w[256];
  __shared__ float bb[8];
  if (threadIdx.x < 256) w[threadIdx.x] = Wcls[threadIdx.x];
  if (threadIdx.x < 8) bb[threadIdx.x] = bcls[threadIdx.x];
  __syncthreads();
  int t = blockIdx.x * blockDim.x + threadIdx.x;
  int e = t >> 1, c0 = (t & 1) * 4;
  if (e >= NE) return;
  int s = src[e], d = dst[e];
  const float4* xsv = (const float4*)&x4[s * 16];
  const float4* xdv = (const float4*)&x4[d * 16];
  float acc0 = bb[c0], acc1 = bb[c0 + 1], acc2 = bb[c0 + 2], acc3 = bb[c0 + 3];
#pragma unroll
  for (int q = 0; q < 4; ++q) {
    float4 xv = xsv[q];
#pragma unroll
    for (int j = 0; j < 4; ++j) {
      float x = j == 0 ? xv.x : j == 1 ? xv.y : j == 2 ? xv.z : xv.w;
      const float* wr = &w[(q * 4 + j) * 8 + c0];
      acc0 += x * wr[0];
      acc1 += x * wr[1];
      acc2 += x * wr[2];
      acc3 += x * wr[3];
    }
  }
#pragma unroll
  for (int q = 0; q < 4; ++q) {
    float4 xv = xdv[q];
#pragma unroll
    for (int j = 0; j < 4; ++j) {
      float x = j == 0 ? xv.x : j == 1 ? xv.y : j == 2 ? xv.z : xv.w;
      const float* wr = &w[(16 + q * 4 + j) * 8 + c0];
      acc0 += x * wr[0];
      acc1 += x * wr[1];
      acc2 += x * wr[2];
      acc3 += x * wr[3];
    }
  }
  *(float4*)&out[e * 8 + c0] = make_float4(acc0, acc1, acc2, acc3);
}

extern "C" void kernel_launch(void* const* d_in, const int* in_sizes, int n_in,
                              void* d_out, int out_size, void* d_ws, size_t ws_size,
                              hipStream_t stream) {
  const float* h      = (const float*)d_in[0];
  const float* edge_w = (const float*)d_in[1];
  const int*   src    = (const int*)d_in[2];
  const int*   dst    = (const int*)d_in[3];
  const float* Wn    = (const float*)d_in[4];
  const float* bn    = (const float*)d_in[5];
  const float* W1s   = (const float*)d_in[6];
  const float* b1s   = (const float*)d_in[7];
  const float* W1d   = (const float*)d_in[8];
  const float* b1d   = (const float*)d_in[9];
  const float* attn1 = (const float*)d_in[10];
  const float* W2s   = (const float*)d_in[11];
  const float* b2s   = (const float*)d_in[12];
  const float* W2d   = (const float*)d_in[13];
  const float* b2d   = (const float*)d_in[14];
  const float* attn2 = (const float*)d_in[15];
  const float* Wc1   = (const float*)d_in[16];
  const float* bc1   = (const float*)d_in[17];
  const float* Wc2   = (const float*)d_in[18];
  const float* bc2   = (const float*)d_in[19];
  const float* Wcls  = (const float*)d_in[20];
  const float* bcls  = (const float*)d_in[21];
  float* out = (float*)d_out;

  float* ws = (float*)d_ws;
  size_t off = 0;
  // round every allocation to 4 floats so int2/float4 views stay 16B-aligned
  auto alloc = [&](size_t nf) { float* pp = ws + off; off += (nf + 3) & ~(size_t)3; return pp; };
  float* Wns = alloc(8192);
  float* Wnd = alloc(8192);
  float* bns = alloc(64);
  float* bnd = alloc(64);
  unsigned long long* degw = (unsigned long long*)alloc(2 * NN);  // u64 per node
  int*   cnt = (int*)alloc(NN);
  float* deg = alloc(2 * NN);          // decoded wdeg_out | cnt_out (fully written)
  int*   row_start = (int*)alloc(NN + 1);
  int2*  psrcw = (int2*)alloc(2 * NE); // dst-sorted (src, weight_bits)
  float* FS  = alloc(64 * NN);         // fs1 -> fs2 -> ym(32N) -> xs(16N)
  float* FD  = alloc(64 * NN);         // fd1 -> fd2 -> x3a(32N)
  float* G   = alloc(64 * NN);         // rank -> g1 -> g2 -> x4(16N)
  int*   rank = (int*)G;               // rank dead before gat1 writes G

  dim3 b256(256);
  const int EB = (NE + 255) / 256;     // 3125
  const int NB4 = (NN + 3) / 4;        // 12500

  // 1. zero cnt (edge_rank dependency)
  zero_cnt<<<(NN + 255) / 256, b256, 0, stream>>>(cnt);
  // 2. combine weights || zero degw || per-edge dst rank
  fatA_kernel<<<FATA_CB + FATA_ZB + EB, b256, 0, stream>>>(
      Wn, bn, W1s, b1s, W1d, b1d, Wns, Wnd, bns, bnd, (float*)degw, dst, cnt, rank);
  // 3. row_start = exclusive scan of cnt (single block)
  scan_all<<<1, 1024, 0, stream>>>(cnt, row_start);
  // 4. place edges (no position atomic) + degw atomics  ||  layer-1 dual GEMM
  fatB_kernel<<<2 * EB, b256, 0, stream>>>(src, dst, edge_w, row_start, rank, psrcw,
                                           degw, h, Wns, bns, Wnd, bnd, FS, FD);
  // 5. GAT layer 1
  gat_fused<1><<<NB4, b256, 0, stream>>>(row_start, psrcw, FS, FD, attn1, G);
  // 6. layer-2 dual GEMM || decode degrees
  fatL2_kernel<<<3125 + (NN + 255) / 256, b256, 0, stream>>>(G, W2s, b2s, W2d, b2d,
                                                             FS, FD, degw, deg);
  // 7. GAT layer 2
  gat_fused<0><<<NB4, b256, 0, stream>>>(row_start, psrcw, FS, FD, attn2, G);
  // 8. ym = elu(g2) @ Wc1 * rsqrt(outw)
  node_gemm<64, 32, true, 2, false><<<(NN + 31) / 32, b256, 0, stream>>>(
      G, Wc1, nullptr, nullptr, nullptr, deg, FS, nullptr);
  // 9. GraphConv1 aggregate (x3a -> FD)
  gconv1_fused<<<NB4, b256, 0, stream>>>(row_start, psrcw, FS, bc1, FD);
  // 10. xs = (x3a @ Wc2) * rsqrt(max(dout,1))  (xs -> FS)
  node_gemm<32, 16, false, 1, false><<<(NN + 63) / 64, b256, 0, stream>>>(
      FD, Wc2, nullptr, nullptr, nullptr, deg + NN, FS, nullptr);
  // 11. GraphConv2 aggregate (x4 -> G)
  gconv2_fused<<<NB4, b256, 0, stream>>>(row_start, psrcw, FS, bc2, G);
  // 12. per-edge classifier
  classifier_kernel<<<(NE * 2 + 255) / 256, b256, 0, stream>>>(src, dst, G, Wcls, bcls, out);
}